// Round 1
// baseline (128.570 us; speedup 1.0000x reference)
//
#include <hip/hip_runtime.h>
#include <hip/hip_bf16.h>

typedef float f32x4 __attribute__((ext_vector_type(4)));
typedef short s16x8 __attribute__((ext_vector_type(8)));

#define WAVES 4
#define LANE_STRIDE 20   // words per lane in LDS transpose buffer (pad vs 16 to spread banks)

__device__ __forceinline__ f32x4 mfma16(s16x8 a, s16x8 b, f32x4 c) {
    return __builtin_amdgcn_mfma_f32_16x16x32_bf16(a, b, c, 0, 0, 0);
}

__device__ __forceinline__ short bfs(float x) {
    return (short)__builtin_bit_cast(unsigned short, __float2bfloat16(x));
}

// Split 8 fp32 (two f32x4) into hi/lo bf16 fragments: x ≈ hi + lo, |lo| <= 2^-9 |x|
__device__ __forceinline__ void split8(f32x4 a, f32x4 b, s16x8& h, s16x8& l) {
#pragma unroll
    for (int j = 0; j < 8; ++j) {
        float x = (j < 4) ? a[j] : b[j - 4];
        __hip_bfloat16 hb = __float2bfloat16(x);      // RNE
        float hf = __bfloat162float(hb);              // exact
        h[j] = (short)__builtin_bit_cast(unsigned short, hb);
        l[j] = bfs(x - hf);                           // exact residual, then RNE
    }
}

// One wave processes 16 batch rows per tile.
// Orientation: D[m=neuron][n=batch].  A = weight fragments (static, in regs),
// B = activations^T fragments.  mfma_f32_16x16x32_bf16 layouts:
//   A: lane l supplies A[l&15][8*(l>>4)+j]
//   B: lane l supplies B[8*(l>>4)+j][l&15]
//   D: lane l holds   D[4*(l>>4)+r][l&15]   (HW-verified mapping)
__global__ __launch_bounds__(256, 2) void mlp_kernel(
    const float* __restrict__ X, const float* __restrict__ W0,
    const float* __restrict__ W1, const float* __restrict__ W2,
    float* __restrict__ Y, int ntiles)
{
    __shared__ float lds_all[WAVES][64 * LANE_STRIDE];
    const int tid  = threadIdx.x;
    const int wid  = tid >> 6;
    const int lane = tid & 63;
    const int b16  = lane & 15;
    const int g    = lane >> 4;

    float* lds = lds_all[wid];

    // ---- build static weight fragments (hi/lo) ----
    s16x8 w0h[4], w0l[4], w1h[4][2], w1l[4][2], w2h[2], w2l[2];
#pragma unroll
    for (int t = 0; t < 4; ++t) {
        const float* p = W0 + (16*t + b16)*32 + 8*g;
        split8(*(const f32x4*)p, *(const f32x4*)(p+4), w0h[t], w0l[t]);
    }
#pragma unroll
    for (int t = 0; t < 4; ++t) {
#pragma unroll
        for (int s = 0; s < 2; ++s) {
            const float* p = W1 + (16*t + b16)*64 + 32*s + 8*g;
            split8(*(const f32x4*)p, *(const f32x4*)(p+4), w1h[t][s], w1l[t][s]);
        }
    }
#pragma unroll
    for (int s = 0; s < 2; ++s) {
        const float* p = W2 + b16*64 + 32*s + 8*g;
        split8(*(const f32x4*)p, *(const f32x4*)(p+4), w2h[s], w2l[s]);
    }

    const int gwid = blockIdx.x * WAVES + wid;
    const int gstr = gridDim.x * WAVES;
    int tile = gwid;
    if (tile >= ntiles) return;

    const int xoff  = b16*32 + 8*g;            // lane's float offset inside a 16x32 input tile
    const int yoff  = b16*16 + 4*g;            // lane's float offset inside a 16x16 output tile
    // transition read addresses:  act[n=32s+8g+j][b16], j=4h+r comes from
    // src lane (b16+32*(g&1)+16h), words 4*(2s+(g>>1)) + r
    const int loA = (b16 + 32*(g&1)) * LANE_STRIDE + 4*(g>>1);
    const int loB = loA + 16*LANE_STRIDE;

    f32x4 cx0 = *(const f32x4*)(X + (size_t)tile*512 + xoff);
    f32x4 cx1 = *(const f32x4*)(X + (size_t)tile*512 + xoff + 4);

    while (true) {
        int next = tile + gstr;
        bool have_next = next < ntiles;
        const float* np = X + (size_t)(have_next ? next : tile)*512 + xoff;
        f32x4 nx0 = *(const f32x4*)np;          // prefetch next tile
        f32x4 nx1 = *(const f32x4*)(np + 4);

        // ---- layer 1: 64 = 4 m-tiles, K=32 (1 step) ----
        s16x8 xh, xl;
        split8(cx0, cx1, xh, xl);
        f32x4 acc[4];
#pragma unroll
        for (int t = 0; t < 4; ++t) {
            f32x4 c = {0.f, 0.f, 0.f, 0.f};
            c = mfma16(w0h[t], xh, c);
            c = mfma16(w0l[t], xh, c);
            c = mfma16(w0h[t], xl, c);
            acc[t] = c;
        }
        // relu + scatter to per-wave LDS (lane-contiguous, b128)
#pragma unroll
        for (int t = 0; t < 4; ++t) {
            f32x4 r;
#pragma unroll
            for (int i = 0; i < 4; ++i) r[i] = fmaxf(acc[t][i], 0.f);
            *(f32x4*)(lds + lane*LANE_STRIDE + 4*t) = r;
        }

        // ---- layer 2: 4 m-tiles, K=64 (2 steps) ----
        f32x4 a2[4];
#pragma unroll
        for (int t = 0; t < 4; ++t) a2[t] = (f32x4){0.f, 0.f, 0.f, 0.f};
#pragma unroll
        for (int s = 0; s < 2; ++s) {
            f32x4 va = *(const f32x4*)(lds + loA + 8*s);
            f32x4 vb = *(const f32x4*)(lds + loB + 8*s);
            s16x8 bh, bl;
            split8(va, vb, bh, bl);
#pragma unroll
            for (int t = 0; t < 4; ++t) {
                a2[t] = mfma16(w1h[t][s], bh, a2[t]);
                a2[t] = mfma16(w1l[t][s], bh, a2[t]);
                a2[t] = mfma16(w1h[t][s], bl, a2[t]);
            }
        }
#pragma unroll
        for (int t = 0; t < 4; ++t) {
            f32x4 r;
#pragma unroll
            for (int i = 0; i < 4; ++i) r[i] = fmaxf(a2[t][i], 0.f);
            *(f32x4*)(lds + lane*LANE_STRIDE + 4*t) = r;
        }

        // ---- layer 3: 1 m-tile (16 outs), K=64 (2 steps) ----
        f32x4 a3 = {0.f, 0.f, 0.f, 0.f};
#pragma unroll
        for (int s = 0; s < 2; ++s) {
            f32x4 va = *(const f32x4*)(lds + loA + 8*s);
            f32x4 vb = *(const f32x4*)(lds + loB + 8*s);
            s16x8 bh, bl;
            split8(va, vb, bh, bl);
            a3 = mfma16(w2h[s], bh, a3);
            a3 = mfma16(w2l[s], bh, a3);
            a3 = mfma16(w2h[s], bl, a3);
        }
        *(f32x4*)(Y + (size_t)tile*256 + yoff) = a3;

        if (!have_next) break;
        tile = next;
        cx0 = nx0; cx1 = nx1;
    }
}

extern "C" void kernel_launch(void* const* d_in, const int* in_sizes, int n_in,
                              void* d_out, int out_size, void* d_ws, size_t ws_size,
                              hipStream_t stream) {
    const float* X  = (const float*)d_in[0];
    const float* W0 = (const float*)d_in[1];
    const float* W1 = (const float*)d_in[2];
    const float* W2 = (const float*)d_in[3];
    float* Y = (float*)d_out;

    const int batch  = in_sizes[0] / 32;
    const int ntiles = batch / 16;           // 2,000,000 / 16 = 125,000
    int blocks = 1024;
    if (blocks * WAVES > ntiles) blocks = (ntiles + WAVES - 1) / WAVES;

    hipLaunchKernelGGL(mlp_kernel, dim3(blocks), dim3(256), 0, stream,
                       X, W0, W1, W2, Y, ntiles);
}

// Round 2
// 82.755 us; speedup vs baseline: 1.5536x; 1.5536x over previous
//
#include <hip/hip_runtime.h>
#include <hip/hip_bf16.h>

typedef float f32x4 __attribute__((ext_vector_type(4)));
typedef _Float16 f16x8 __attribute__((ext_vector_type(8)));
typedef _Float16 f16x4 __attribute__((ext_vector_type(4)));

#define WAVES 4
#define COLSTR 36   // dwords per b16-column in LDS transition buffer (even -> 8B align; spreads banks)

__device__ __forceinline__ f32x4 mfma16(f16x8 a, f16x8 b, f32x4 c) {
    return __builtin_amdgcn_mfma_f32_16x16x32_f16(a, b, c, 0, 0, 0);
}

// 8 consecutive k-elements (fp32) -> fp16 fragment, RNE
__device__ __forceinline__ f16x8 cvt8(f32x4 a, f32x4 b) {
    f16x8 h;
#pragma unroll
    for (int j = 0; j < 4; ++j) { h[j] = (_Float16)a[j]; h[j + 4] = (_Float16)b[j]; }
    return h;
}

// relu + pack 4 accumulator floats -> 4 fp16 (RNE), for one m-quad
__device__ __forceinline__ f16x4 relu_pk(f32x4 a) {
    f16x4 v;
#pragma unroll
    for (int j = 0; j < 4; ++j) v[j] = (_Float16)fmaxf(a[j], 0.0f);
    return v;
}

// One wave processes TWO 16-row batch tiles per iteration (independent chains for ILP).
// Orientation: D[m=neuron][n=batch]. A = fp16 weight fragments (regs, loaded once),
// B = fp16 activations^T. mfma_f32_16x16x32_f16 layouts (verified by round-1 pass):
//   A: lane l supplies A[l&15][8*(l>>4)+j]
//   B: lane l supplies B[8*(l>>4)+j][l&15]
//   D: lane l holds   D[4*(l>>4)+r][l&15]
// LDS transition: per b16-column, neurons packed linear as fp16 pairs (dword = neuron>>1):
//   write (lane b16,g; quad t): f16x4 at dword 8t+2g   (ds_write_b64)
//   read  (lane b16,g; step s): f16x8 at dword 16s+4g  (ds_read_b128) == B-fragment directly
__global__ __launch_bounds__(256, 3) void mlp_kernel(
    const float* __restrict__ X, const float* __restrict__ W0,
    const float* __restrict__ W1, const float* __restrict__ W2,
    float* __restrict__ Y, int ntiles)
{
    __shared__ float ldsA[WAVES][2][16 * COLSTR];  // act1 buffers (per wave, per tile)
    __shared__ float ldsB[WAVES][2][16 * COLSTR];  // act2 buffers
    const int tid  = threadIdx.x;
    const int wid  = tid >> 6;
    const int lane = tid & 63;
    const int b16  = lane & 15;
    const int g    = lane >> 4;

    // ---- fp16 weight fragments (RNE), loaded once per wave ----
    f16x8 w0[4], w1[4][2], w2[2];
#pragma unroll
    for (int t = 0; t < 4; ++t) {
        const float* p = W0 + (16 * t + b16) * 32 + 8 * g;
        w0[t] = cvt8(*(const f32x4*)p, *(const f32x4*)(p + 4));
    }
#pragma unroll
    for (int t = 0; t < 4; ++t) {
#pragma unroll
        for (int s = 0; s < 2; ++s) {
            const float* p = W1 + (16 * t + b16) * 64 + 32 * s + 8 * g;
            w1[t][s] = cvt8(*(const f32x4*)p, *(const f32x4*)(p + 4));
        }
    }
#pragma unroll
    for (int s = 0; s < 2; ++s) {
        const float* p = W2 + b16 * 64 + 32 * s + 8 * g;
        w2[s] = cvt8(*(const f32x4*)p, *(const f32x4*)(p + 4));
    }

    const int xoff  = b16 * 32 + 8 * g;          // float offset within a 16x32 input tile
    const int yoff  = b16 * 16 + 4 * g;          // float offset within a 16x16 output tile
    const int wbase = COLSTR * b16 + 2 * g;      // + 8t for act writes
    const int rbase = COLSTR * b16 + 4 * g;      // + 16s for B-frag reads

    float* A0 = &ldsA[wid][0][0];
    float* A1 = &ldsA[wid][1][0];
    float* B0 = &ldsB[wid][0][0];
    float* B1 = &ldsB[wid][1][0];

    const int npairs = (ntiles + 1) >> 1;
    const int gwid = blockIdx.x * WAVES + wid;
    const int gstr = gridDim.x * WAVES;
    if (gwid >= npairs) return;

    int pair = gwid;
    {
        // first-pair loads happen in-loop via the "current" regs below
    }
    const float* xp = X + (size_t)(2 * pair) * 512 + xoff;
    size_t off1 = (2 * pair + 1 < ntiles) ? 512 : 0;   // duplicate-safe for odd tail
    f32x4 x00 = *(const f32x4*)xp;
    f32x4 x01 = *(const f32x4*)(xp + 4);
    f32x4 x10 = *(const f32x4*)(xp + off1);
    f32x4 x11 = *(const f32x4*)(xp + off1 + 4);

    while (true) {
        const int next = pair + gstr;
        const bool have_next = next < npairs;
        const int pf = have_next ? next : pair;
        const float* np = X + (size_t)(2 * pf) * 512 + xoff;
        const size_t noff1 = (2 * pf + 1 < ntiles) ? 512 : 0;
        f32x4 n00 = *(const f32x4*)np;            // prefetch next pair
        f32x4 n01 = *(const f32x4*)(np + 4);
        f32x4 n10 = *(const f32x4*)(np + noff1);
        f32x4 n11 = *(const f32x4*)(np + noff1 + 4);

        // ---- layer 1: K=32, 4 m-quads, one MFMA each, both tiles ----
        f16x8 xa = cvt8(x00, x01);
        f16x8 xb = cvt8(x10, x11);
        f32x4 acc0[4], acc1[4];
#pragma unroll
        for (int t = 0; t < 4; ++t) {
            f32x4 z = {0.f, 0.f, 0.f, 0.f};
            acc0[t] = mfma16(w0[t], xa, z);
            acc1[t] = mfma16(w0[t], xb, z);
        }
#pragma unroll
        for (int t = 0; t < 4; ++t) {
            *(f16x4*)(A0 + wbase + 8 * t) = relu_pk(acc0[t]);
            *(f16x4*)(A1 + wbase + 8 * t) = relu_pk(acc1[t]);
        }

        // ---- layer 2: K=64 (2 steps), 4 m-quads, both tiles ----
        f32x4 c0[4], c1[4];
#pragma unroll
        for (int t = 0; t < 4; ++t) {
            c0[t] = (f32x4){0.f, 0.f, 0.f, 0.f};
            c1[t] = (f32x4){0.f, 0.f, 0.f, 0.f};
        }
#pragma unroll
        for (int s = 0; s < 2; ++s) {
            f16x8 p0 = *(const f16x8*)(A0 + rbase + 16 * s);
            f16x8 p1 = *(const f16x8*)(A1 + rbase + 16 * s);
#pragma unroll
            for (int t = 0; t < 4; ++t) {
                c0[t] = mfma16(w1[t][s], p0, c0[t]);
                c1[t] = mfma16(w1[t][s], p1, c1[t]);
            }
        }
#pragma unroll
        for (int t = 0; t < 4; ++t) {
            *(f16x4*)(B0 + wbase + 8 * t) = relu_pk(c0[t]);
            *(f16x4*)(B1 + wbase + 8 * t) = relu_pk(c1[t]);
        }

        // ---- layer 3: 16 outputs, K=64 (2 steps), both tiles ----
        f32x4 o0 = {0.f, 0.f, 0.f, 0.f};
        f32x4 o1 = {0.f, 0.f, 0.f, 0.f};
#pragma unroll
        for (int s = 0; s < 2; ++s) {
            f16x8 q0 = *(const f16x8*)(B0 + rbase + 16 * s);
            f16x8 q1 = *(const f16x8*)(B1 + rbase + 16 * s);
            o0 = mfma16(w2[s], q0, o0);
            o1 = mfma16(w2[s], q1, o1);
        }
        float* yp = Y + (size_t)(2 * pair) * 256 + yoff;
        *(f32x4*)yp = o0;
        *(f32x4*)(yp + (off1 ? 256 : 0)) = o1;

        if (!have_next) break;
        pair = next;
        off1 = noff1;
        x00 = n00; x01 = n01; x10 = n10; x11 = n11;
    }
}

extern "C" void kernel_launch(void* const* d_in, const int* in_sizes, int n_in,
                              void* d_out, int out_size, void* d_ws, size_t ws_size,
                              hipStream_t stream) {
    const float* X  = (const float*)d_in[0];
    const float* W0 = (const float*)d_in[1];
    const float* W1 = (const float*)d_in[2];
    const float* W2 = (const float*)d_in[3];
    float* Y = (float*)d_out;

    const int batch  = in_sizes[0] / 32;
    const int ntiles = batch / 16;               // 125,000
    const int npairs = (ntiles + 1) >> 1;        // 62,500

    int blocks = 768;                            // 3 blocks/CU resident at 3 waves/SIMD
    if (blocks * WAVES > npairs) blocks = (npairs + WAVES - 1) / WAVES;

    hipLaunchKernelGGL(mlp_kernel, dim3(blocks), dim3(256), 0, stream,
                       X, W0, W1, W2, Y, ntiles);
}